// Round 8
// baseline (209.396 us; speedup 1.0000x reference)
//
#include <hip/hip_runtime.h>

typedef __attribute__((ext_vector_type(8))) short short8;
typedef __attribute__((ext_vector_type(16))) float f32x16;
typedef __attribute__((ext_vector_type(4))) int int4v;

#define LOG2E 1.4426950408889634f

#if __has_builtin(__builtin_amdgcn_exp2f)
#define EXP2(x) __builtin_amdgcn_exp2f(x)
#else
#define EXP2(x) exp2f(x)
#endif

__device__ __forceinline__ unsigned cvtpk(float lo, float hi) {
    unsigned r;
    asm("v_cvt_pk_bf16_f32 %0, %1, %2" : "=v"(r) : "v"(lo), "v"(hi));
    return r;
}

// ============================================================================
// Split kernel: B=2 H=16 S=2048 D=64. Wave = 32 q rows, block = 4 waves.
// grid = 1024 blocks = 32 bh x 16 qblk x 2 key-splits of 1024 keys each.
// Static-shift softmax (p = exp2(s + bias), bias = -24 or -inf) makes split
// partials additive: block writes UNNORMALIZED (O_part, l_part) to workspace.
// LDS 37.4 KB -> 4 blocks/CU; launch_bounds(256,4) caps VGPR at 128.
// ============================================================================
__global__ __launch_bounds__(256, 4) void attn_fwd_split(
    const float* __restrict__ Q, const float* __restrict__ K,
    const float* __restrict__ V, const int* __restrict__ M,
    float* __restrict__ Opart, float* __restrict__ lpart)
{
    constexpr int S = 2048, D = 64, KVB = 64, SPLIT = 1024, NT = SPLIT / KVB;
    __shared__ unsigned short k_lds[2][KVB * D];   // [key][d] swizzled
    __shared__ unsigned short vt_lds[2][D * KVB];  // [d][key] swizzled
    __shared__ float bias_lds[SPLIT];
    __shared__ float pad_[16];                     // keep LDS layout aligned

    const int t = threadIdx.x;
    const int lane = t & 63, wid = t >> 6;
    const int l31 = lane & 31, hi = lane >> 5;

    // XCD-bijective swizzle: 1024 blocks = 8 XCD chunks of 128.
    const int lin = blockIdx.x;
    const int wgid = (lin & 7) * 128 + (lin >> 3);
    const int split = wgid >> 9;          // 0..1
    const int bh = (wgid >> 4) & 31;      // 0..31
    const int qblk = wgid & 15;           // 0..15
    const int b = bh >> 4;                // H = 16
    const int soff = split * SPLIT;

    // mask bias (this split's keys): keep -> -24, pad -> -inf
    const int* mrow = M + b * S + soff;
    for (int i = t; i < SPLIT; i += 256)
        bias_lds[i] = mrow[i] ? -24.0f : -__builtin_inff();

    // Q B-fragments (col=q=l31, k=hi*8+j per 16-d chunk), scaled by 0.125*log2e
    const int qrow0 = qblk * 128 + wid * 32;
    const float* qp = Q + ((size_t)bh * S + qrow0 + l31) * D;
    const float qs = 0.125f * LOG2E;
    short8 qf[4];
    #pragma unroll
    for (int c = 0; c < 4; ++c) {
        const float* p = qp + c * 16 + hi * 8;
        float4 x = *(const float4*)p;
        float4 y = *(const float4*)(p + 4);
        int4v w = { (int)cvtpk(x.x * qs, x.y * qs), (int)cvtpk(x.z * qs, x.w * qs),
                    (int)cvtpk(y.x * qs, y.y * qs), (int)cvtpk(y.z * qs, y.w * qs) };
        qf[c] = __builtin_bit_cast(short8, w);
    }

    f32x16 acc0 = {0,0,0,0,0,0,0,0,0,0,0,0,0,0,0,0};
    f32x16 acc1 = {0,0,0,0,0,0,0,0,0,0,0,0,0,0,0,0};
    float l = 0.0f;

    // staging coords
    const int skey = t >> 2, sds2 = (t & 3) * 32;
    const int swzk = (skey & 7) << 4;
    const int kwb = skey * 128;
    const int vkey2 = lane * 2;
    const int vds = wid * 16;

    // per-lane swizzled read bases
    const int krow0 = l31 * 128;
    const int krow1 = (32 + l31) * 128;
    const int kx = (hi * 16) ^ ((l31 & 7) << 4);
    const int vrow0 = l31 * 128;
    const int vrow1 = (32 + l31) * 128;

    const float* kpt = K + (size_t)bh * S * D + (size_t)(soff + skey) * D + (t & 3) * 16;
    const float* vpt = V + (size_t)bh * S * D + (size_t)(soff + lane) * D + vds;

    float4 ka0, ka1, ka2, ka3, vb0, vb1, vb2, vb3;

    auto load_tile = [&]() {
        ka0 = ((const float4*)kpt)[0]; ka1 = ((const float4*)kpt)[1];
        ka2 = ((const float4*)kpt)[2]; ka3 = ((const float4*)kpt)[3];
        vb0 = ((const float4*)vpt)[0]; vb1 = ((const float4*)vpt)[1];
        vb2 = ((const float4*)vpt)[2]; vb3 = ((const float4*)vpt)[3];
        kpt += KVB * D; vpt += KVB * D;
    };
    auto write_tile = [&](unsigned short* kdst, unsigned short* vdst) {
        int4v w0 = { (int)cvtpk(ka0.x,ka0.y), (int)cvtpk(ka0.z,ka0.w),
                     (int)cvtpk(ka1.x,ka1.y), (int)cvtpk(ka1.z,ka1.w) };
        int4v w1 = { (int)cvtpk(ka2.x,ka2.y), (int)cvtpk(ka2.z,ka2.w),
                     (int)cvtpk(ka3.x,ka3.y), (int)cvtpk(ka3.z,ka3.w) };
        *(int4v*)((char*)kdst + kwb + (sds2 ^ swzk)) = w0;
        *(int4v*)((char*)kdst + kwb + ((sds2 + 16) ^ swzk)) = w1;
        unsigned cc[8] = { cvtpk(vb0.x,vb0.y), cvtpk(vb0.z,vb0.w),
                           cvtpk(vb1.x,vb1.y), cvtpk(vb1.z,vb1.w),
                           cvtpk(vb2.x,vb2.y), cvtpk(vb2.z,vb2.w),
                           cvtpk(vb3.x,vb3.y), cvtpk(vb3.z,vb3.w) };
        #pragma unroll
        for (int i = 0; i < 16; ++i) {
            int row = vds + i;
            int off = row * 128 + (vkey2 ^ ((i & 7) << 4));  // (row&7)==(i&7): vds%8==0
            unsigned val = (i & 1) ? (cc[i >> 1] >> 16) : (cc[i >> 1] & 0xffffu);
            *(unsigned short*)((char*)vdst + off) = (unsigned short)val;
        }
    };

    load_tile();
    write_tile(k_lds[0], vt_lds[0]);
    __syncthreads();

    #pragma unroll 2
    for (int it = 0; it < NT; ++it) {
        const int cur = it & 1;
        const bool more = (it + 1 < NT);
        if (more) load_tile();   // issue-early

        const char* kc = (const char*)k_lds[cur];
        const char* vc = (const char*)vt_lds[cur];
        const int ktoff = it * KVB;

        // QK^T (swapped): S^T = K * Q^T
        f32x16 s0 = {0,0,0,0,0,0,0,0,0,0,0,0,0,0,0,0};
        f32x16 s1 = {0,0,0,0,0,0,0,0,0,0,0,0,0,0,0,0};
        __builtin_amdgcn_s_setprio(1);
        #pragma unroll
        for (int c = 0; c < 4; ++c) {
            short8 kaf = *(const short8*)(kc + krow0 + (kx ^ (c << 5)));
            short8 kbf = *(const short8*)(kc + krow1 + (kx ^ (c << 5)));
            s0 = __builtin_amdgcn_mfma_f32_32x32x16_bf16(kaf, qf[c], s0, 0, 0, 0);
            s1 = __builtin_amdgcn_mfma_f32_32x32x16_bf16(kbf, qf[c], s1, 0, 0, 0);
        }
        __builtin_amdgcn_s_setprio(0);

        // bias + exp2 + row-sum (lane-local)
        float rsp0 = 0.0f, rsp1 = 0.0f, rsp2 = 0.0f, rsp3 = 0.0f;
        #pragma unroll
        for (int rg = 0; rg < 4; ++rg) {
            float4 bz0 = *(const float4*)&bias_lds[ktoff + rg * 8 + hi * 4];
            float4 bz1 = *(const float4*)&bias_lds[ktoff + 32 + rg * 8 + hi * 4];
            const float* z0 = (const float*)&bz0;
            const float* z1 = (const float*)&bz1;
            float rp = 0.0f;
            #pragma unroll
            for (int j = 0; j < 4; ++j) {
                int r = rg * 4 + j;
                float e0 = EXP2(s0[r] + z0[j]);
                float e1 = EXP2(s1[r] + z1[j]);
                s0[r] = e0; s1[r] = e1;
                rp += e0 + e1;
            }
            if (rg == 0) rsp0 = rp; else if (rg == 1) rsp1 = rp;
            else if (rg == 2) rsp2 = rp; else rsp3 = rp;
        }
        float rs = (rsp0 + rsp1) + (rsp2 + rsp3);
        rs += __shfl_xor(rs, 32);
        l += rs;

        // pack P into PV A-frags
        short8 pw[4];
        #pragma unroll
        for (int w = 0; w < 4; ++w) {
            int r0 = (w & 1) * 8;
            float q0 = (w >> 1) ? s1[r0+0] : s0[r0+0];
            float q1 = (w >> 1) ? s1[r0+1] : s0[r0+1];
            float q2 = (w >> 1) ? s1[r0+2] : s0[r0+2];
            float q3 = (w >> 1) ? s1[r0+3] : s0[r0+3];
            float q4 = (w >> 1) ? s1[r0+4] : s0[r0+4];
            float q5 = (w >> 1) ? s1[r0+5] : s0[r0+5];
            float q6 = (w >> 1) ? s1[r0+6] : s0[r0+6];
            float q7 = (w >> 1) ? s1[r0+7] : s0[r0+7];
            unsigned x0 = cvtpk(q0, q1);
            unsigned x1 = cvtpk(q2, q3);
            unsigned x2 = cvtpk(q4, q5);
            unsigned x3 = cvtpk(q6, q7);
            unsigned sx0 = (unsigned)__shfl_xor((int)x0, 32);
            unsigned sx1 = (unsigned)__shfl_xor((int)x1, 32);
            unsigned sx2 = (unsigned)__shfl_xor((int)x2, 32);
            unsigned sx3 = (unsigned)__shfl_xor((int)x3, 32);
            int4v wv = { (int)(hi ? sx2 : x0),
                         (int)(hi ? sx3 : x1),
                         (int)(hi ? x2 : sx0),
                         (int)(hi ? x3 : sx1) };
            pw[w] = __builtin_bit_cast(short8, wv);
        }

        // PV
        __builtin_amdgcn_s_setprio(1);
        #pragma unroll
        for (int w = 0; w < 4; ++w) {
            short8 vf0 = *(const short8*)(vc + vrow0 + (kx ^ (w << 5)));
            short8 vf1 = *(const short8*)(vc + vrow1 + (kx ^ (w << 5)));
            acc0 = __builtin_amdgcn_mfma_f32_32x32x16_bf16(pw[w], vf0, acc0, 0, 0, 0);
            acc1 = __builtin_amdgcn_mfma_f32_32x32x16_bf16(pw[w], vf1, acc1, 0, 0, 0);
        }
        __builtin_amdgcn_s_setprio(0);

        if (more) write_tile(k_lds[cur ^ 1], vt_lds[cur ^ 1]);
        __syncthreads();
    }

    // epilogue: UNNORMALIZED partials to workspace
    float* ob = Opart + ((size_t)split * 32 * S + (size_t)bh * S + qrow0) * D;
    #pragma unroll
    for (int rg = 0; rg < 4; ++rg) {
        #pragma unroll
        for (int j = 0; j < 4; ++j) {
            int r = rg * 4 + j;
            int qr = rg * 8 + hi * 4 + j;
            ob[qr * 64 + l31] = acc0[r];
            ob[qr * 64 + 32 + l31] = acc1[r];
        }
    }
    if (hi == 0)
        lpart[split * 65536 + bh * 2048 + qrow0 + l31] = l;
    (void)pad_;
}

// combine: O = (O0 + O1) / (l0 + l1); 1,048,576 float4s
__global__ __launch_bounds__(256) void attn_combine(
    const float* __restrict__ Opart, const float* __restrict__ lpart,
    float* __restrict__ O)
{
    const int idx4 = blockIdx.x * 256 + threadIdx.x;   // 0..1048575
    const int row = idx4 >> 4;                         // 64 floats = 16 float4 per row
    const float4* A0 = (const float4*)Opart;
    const float4* A1 = A0 + 1048576;
    float inv = 1.0f / (lpart[row] + lpart[65536 + row]);
    float4 a = A0[idx4], b = A1[idx4];
    float4 o;
    o.x = (a.x + b.x) * inv; o.y = (a.y + b.y) * inv;
    o.z = (a.z + b.z) * inv; o.w = (a.w + b.w) * inv;
    ((float4*)O)[idx4] = o;
}

// ============================================================================
// Fallback (proven v3): single kernel, grid 512, used when ws too small.
// ============================================================================
__global__ __launch_bounds__(256) void attn_fwd(
    const float* __restrict__ Q, const float* __restrict__ K,
    const float* __restrict__ V, const int* __restrict__ M,
    float* __restrict__ O)
{
    constexpr int S = 2048, D = 64, KVB = 64, NT = S / KVB;
    __shared__ unsigned short k_lds[2][KVB * D];
    __shared__ unsigned short vt_lds[2][D * KVB];
    __shared__ float bias_lds[S];
    __shared__ float l_buf[4][32];

    const int t = threadIdx.x;
    const int lane = t & 63, wid = t >> 6;
    const int l31 = lane & 31, hi = lane >> 5;

    const int lin = blockIdx.x;
    const int wgid = (lin & 7) * 64 + (lin >> 3);
    const int bh = wgid >> 4;
    const int qblk = wgid & 15;
    const int b = bh >> 4;

    const int* mrow = M + b * S;
    for (int i = t; i < S; i += 256)
        bias_lds[i] = mrow[i] ? -24.0f : -__builtin_inff();

    const int qrow0 = qblk * 128 + wid * 32;
    const float* qp = Q + ((size_t)bh * S + qrow0 + l31) * D;
    const float qs = 0.125f * LOG2E;
    short8 qf[4];
    #pragma unroll
    for (int c = 0; c < 4; ++c) {
        const float* p = qp + c * 16 + hi * 8;
        float4 x = *(const float4*)p;
        float4 y = *(const float4*)(p + 4);
        int4v w = { (int)cvtpk(x.x * qs, x.y * qs), (int)cvtpk(x.z * qs, x.w * qs),
                    (int)cvtpk(y.x * qs, y.y * qs), (int)cvtpk(y.z * qs, y.w * qs) };
        qf[c] = __builtin_bit_cast(short8, w);
    }

    f32x16 acc0 = {0,0,0,0,0,0,0,0,0,0,0,0,0,0,0,0};
    f32x16 acc1 = {0,0,0,0,0,0,0,0,0,0,0,0,0,0,0,0};
    float l = 0.0f;

    const int skey = t >> 2, sds2 = (t & 3) * 32;
    const int swzk = (skey & 7) << 4;
    const int kwb = skey * 128;
    const int vkey2 = lane * 2;
    const int vds = wid * 16;

    const int krow0 = l31 * 128;
    const int krow1 = (32 + l31) * 128;
    const int kx = (hi * 16) ^ ((l31 & 7) << 4);
    const int vrow0 = l31 * 128;
    const int vrow1 = (32 + l31) * 128;

    const float* kpt = K + (size_t)bh * S * D + (size_t)skey * D + (t & 3) * 16;
    const float* vpt = V + (size_t)bh * S * D + (size_t)lane * D + vds;

    float4 ka0, ka1, ka2, ka3, vb0, vb1, vb2, vb3;

    auto load_tile = [&]() {
        ka0 = ((const float4*)kpt)[0]; ka1 = ((const float4*)kpt)[1];
        ka2 = ((const float4*)kpt)[2]; ka3 = ((const float4*)kpt)[3];
        vb0 = ((const float4*)vpt)[0]; vb1 = ((const float4*)vpt)[1];
        vb2 = ((const float4*)vpt)[2]; vb3 = ((const float4*)vpt)[3];
        kpt += KVB * D; vpt += KVB * D;
    };
    auto write_tile = [&](unsigned short* kdst, unsigned short* vdst) {
        int4v w0 = { (int)cvtpk(ka0.x,ka0.y), (int)cvtpk(ka0.z,ka0.w),
                     (int)cvtpk(ka1.x,ka1.y), (int)cvtpk(ka1.z,ka1.w) };
        int4v w1 = { (int)cvtpk(ka2.x,ka2.y), (int)cvtpk(ka2.z,ka2.w),
                     (int)cvtpk(ka3.x,ka3.y), (int)cvtpk(ka3.z,ka3.w) };
        *(int4v*)((char*)kdst + kwb + (sds2 ^ swzk)) = w0;
        *(int4v*)((char*)kdst + kwb + ((sds2 + 16) ^ swzk)) = w1;
        unsigned cc[8] = { cvtpk(vb0.x,vb0.y), cvtpk(vb0.z,vb0.w),
                           cvtpk(vb1.x,vb1.y), cvtpk(vb1.z,vb1.w),
                           cvtpk(vb2.x,vb2.y), cvtpk(vb2.z,vb2.w),
                           cvtpk(vb3.x,vb3.y), cvtpk(vb3.z,vb3.w) };
        #pragma unroll
        for (int i = 0; i < 16; ++i) {
            int row = vds + i;
            int off = row * 128 + (vkey2 ^ ((i & 7) << 4));
            unsigned val = (i & 1) ? (cc[i >> 1] >> 16) : (cc[i >> 1] & 0xffffu);
            *(unsigned short*)((char*)vdst + off) = (unsigned short)val;
        }
    };

    load_tile();
    write_tile(k_lds[0], vt_lds[0]);
    __syncthreads();

    #pragma unroll 2
    for (int it = 0; it < NT; ++it) {
        const int cur = it & 1;
        const bool more = (it + 1 < NT);
        if (more) load_tile();

        const char* kc = (const char*)k_lds[cur];
        const char* vc = (const char*)vt_lds[cur];
        const int ktoff = it * KVB;

        f32x16 s0 = {0,0,0,0,0,0,0,0,0,0,0,0,0,0,0,0};
        f32x16 s1 = {0,0,0,0,0,0,0,0,0,0,0,0,0,0,0,0};
        __builtin_amdgcn_s_setprio(1);
        #pragma unroll
        for (int c = 0; c < 4; ++c) {
            short8 kaf = *(const short8*)(kc + krow0 + (kx ^ (c << 5)));
            short8 kbf = *(const short8*)(kc + krow1 + (kx ^ (c << 5)));
            s0 = __builtin_amdgcn_mfma_f32_32x32x16_bf16(kaf, qf[c], s0, 0, 0, 0);
            s1 = __builtin_amdgcn_mfma_f32_32x32x16_bf16(kbf, qf[c], s1, 0, 0, 0);
        }
        __builtin_amdgcn_s_setprio(0);

        float rsp0 = 0.0f, rsp1 = 0.0f, rsp2 = 0.0f, rsp3 = 0.0f;
        #pragma unroll
        for (int rg = 0; rg < 4; ++rg) {
            float4 bz0 = *(const float4*)&bias_lds[ktoff + rg * 8 + hi * 4];
            float4 bz1 = *(const float4*)&bias_lds[ktoff + 32 + rg * 8 + hi * 4];
            const float* z0 = (const float*)&bz0;
            const float* z1 = (const float*)&bz1;
            float rp = 0.0f;
            #pragma unroll
            for (int j = 0; j < 4; ++j) {
                int r = rg * 4 + j;
                float e0 = EXP2(s0[r] + z0[j]);
                float e1 = EXP2(s1[r] + z1[j]);
                s0[r] = e0; s1[r] = e1;
                rp += e0 + e1;
            }
            if (rg == 0) rsp0 = rp; else if (rg == 1) rsp1 = rp;
            else if (rg == 2) rsp2 = rp; else rsp3 = rp;
        }
        float rs = (rsp0 + rsp1) + (rsp2 + rsp3);
        rs += __shfl_xor(rs, 32);
        l += rs;

        short8 pw[4];
        #pragma unroll
        for (int w = 0; w < 4; ++w) {
            int r0 = (w & 1) * 8;
            float q0 = (w >> 1) ? s1[r0+0] : s0[r0+0];
            float q1 = (w >> 1) ? s1[r0+1] : s0[r0+1];
            float q2 = (w >> 1) ? s1[r0+2] : s0[r0+2];
            float q3 = (w >> 1) ? s1[r0+3] : s0[r0+3];
            float q4 = (w >> 1) ? s1[r0+4] : s0[r0+4];
            float q5 = (w >> 1) ? s1[r0+5] : s0[r0+5];
            float q6 = (w >> 1) ? s1[r0+6] : s0[r0+6];
            float q7 = (w >> 1) ? s1[r0+7] : s0[r0+7];
            unsigned x0 = cvtpk(q0, q1);
            unsigned x1 = cvtpk(q2, q3);
            unsigned x2 = cvtpk(q4, q5);
            unsigned x3 = cvtpk(q6, q7);
            unsigned sx0 = (unsigned)__shfl_xor((int)x0, 32);
            unsigned sx1 = (unsigned)__shfl_xor((int)x1, 32);
            unsigned sx2 = (unsigned)__shfl_xor((int)x2, 32);
            unsigned sx3 = (unsigned)__shfl_xor((int)x3, 32);
            int4v wv = { (int)(hi ? sx2 : x0),
                         (int)(hi ? sx3 : x1),
                         (int)(hi ? x2 : sx0),
                         (int)(hi ? x3 : sx1) };
            pw[w] = __builtin_bit_cast(short8, wv);
        }

        __builtin_amdgcn_s_setprio(1);
        #pragma unroll
        for (int w = 0; w < 4; ++w) {
            short8 vf0 = *(const short8*)(vc + vrow0 + (kx ^ (w << 5)));
            short8 vf1 = *(const short8*)(vc + vrow1 + (kx ^ (w << 5)));
            acc0 = __builtin_amdgcn_mfma_f32_32x32x16_bf16(pw[w], vf0, acc0, 0, 0, 0);
            acc1 = __builtin_amdgcn_mfma_f32_32x32x16_bf16(pw[w], vf1, acc1, 0, 0, 0);
        }
        __builtin_amdgcn_s_setprio(0);

        if (more) write_tile(k_lds[cur ^ 1], vt_lds[cur ^ 1]);
        __syncthreads();
    }

    if (hi == 0) l_buf[wid][l31] = 1.0f / l;
    __syncthreads();

    float* ob = O + ((size_t)bh * S + qrow0) * D;
    #pragma unroll
    for (int rg = 0; rg < 4; ++rg) {
        float4 invl = *(const float4*)&l_buf[wid][rg * 8 + hi * 4];
        const float* iv = (const float*)&invl;
        #pragma unroll
        for (int j = 0; j < 4; ++j) {
            int r = rg * 4 + j;
            int qr = rg * 8 + hi * 4 + j;
            ob[qr * 64 + l31] = acc0[r] * iv[j];
            ob[qr * 64 + 32 + l31] = acc1[r] * iv[j];
        }
    }
}

extern "C" void kernel_launch(void* const* d_in, const int* in_sizes, int n_in,
                              void* d_out, int out_size, void* d_ws, size_t ws_size,
                              hipStream_t stream) {
    const float* Q = (const float*)d_in[0];
    const float* K = (const float*)d_in[1];
    const float* V = (const float*)d_in[2];
    const int*   M = (const int*)d_in[3];
    float* O = (float*)d_out;

    // workspace need: 2 splits x (32*2048*64 O floats) + 2 x 65536 l floats
    const size_t need = (size_t)2 * 32 * 2048 * 64 * 4 + (size_t)2 * 65536 * 4;
    if (ws_size >= need) {
        float* Opart = (float*)d_ws;
        float* lpart = Opart + (size_t)2 * 32 * 2048 * 64;
        attn_fwd_split<<<dim3(1024), dim3(256), 0, stream>>>(Q, K, V, M, Opart, lpart);
        attn_combine<<<dim3(4096), dim3(256), 0, stream>>>(Opart, lpart, O);
    } else {
        attn_fwd<<<dim3(512), dim3(256), 0, stream>>>(Q, K, V, M, O);
    }
}

// Round 9
// 207.034 us; speedup vs baseline: 1.0114x; 1.0114x over previous
//
#include <hip/hip_runtime.h>

typedef __attribute__((ext_vector_type(8))) short short8;
typedef __attribute__((ext_vector_type(16))) float f32x16;
typedef __attribute__((ext_vector_type(4))) int int4v;

#define LOG2E 1.4426950408889634f

#if __has_builtin(__builtin_amdgcn_exp2f)
#define EXP2(x) __builtin_amdgcn_exp2f(x)
#else
#define EXP2(x) exp2f(x)
#endif

__device__ __forceinline__ unsigned cvtpk(float lo, float hi) {
    unsigned r;
    asm("v_cvt_pk_bf16_f32 %0, %1, %2" : "=v"(r) : "v"(lo), "v"(hi));
    return r;
}

// B=2 H=16 S=2048 D=64. 512-thread block = 8 waves: waves 0-3 = key-half A
// (keys 0..1023), waves 4-7 = half B (1024..2047); each wave owns 32 q rows.
// Per half: double-buffered K [key][d] + V^T [d][key] bf16 LDS, XOR-swizzled.
// Swapped QK^T (S^T = K*Q^T), static-shift softmax p = exp2(s + bias),
// bias = -24 (keep) / -inf (pad) -> split partials are ADDITIVE (no max fixup).
// Combine IN LDS: half-B writes unnormalized acc (aliased over K/V region) + l;
// half-A adds, normalizes by (lA+lB), stores. No workspace traffic.
__global__ __launch_bounds__(512, 4) void attn_fwd8(
    const float* __restrict__ Q, const float* __restrict__ K,
    const float* __restrict__ V, const int* __restrict__ M,
    float* __restrict__ O)
{
    constexpr int S = 2048, D = 64, KVB = 64, NT = 16;  // 16 tiles per half
    // carve: kreg [h][dbuf][64*64]ushort = 32KB, vreg same = 32KB; obuf aliases
    __shared__ __align__(16) char smem[65536];
    __shared__ float bias_lds[S];
    __shared__ float l_buf[8][32];

    unsigned short* kreg = (unsigned short*)smem;
    unsigned short* vreg = (unsigned short*)(smem + 32768);
    float* obuf = (float*)smem;   // 128 q x 64 d fp32, valid after final barrier

    const int t = threadIdx.x;
    const int lane = t & 63, wid = t >> 6;
    const int l31 = lane & 31, hi = lane >> 5;
    const int h = wid >> 2, qw = wid & 3;   // key-half, q-wave within half
    const int t255 = t & 255;               // thread index within half

    // XCD-bijective swizzle: 512 blocks = 8 XCD chunks of 64
    const int lin = blockIdx.x;
    const int wgid = (lin & 7) * 64 + (lin >> 3);
    const int bh = wgid >> 4;     // 0..31
    const int qblk = wgid & 15;   // 0..15
    const int b = bh >> 4;        // H = 16

    const int* mrow = M + b * S;
    for (int i = t; i < S; i += 512)
        bias_lds[i] = mrow[i] ? -24.0f : -__builtin_inff();

    // Q B-fragments (col=q=l31, k=hi*8+j per 16-d chunk), scaled by 0.125*log2e
    const int qrow0 = qblk * 128 + qw * 32;
    const float* qp = Q + ((size_t)bh * S + qrow0 + l31) * D;
    const float qs = 0.125f * LOG2E;
    short8 qf[4];
    #pragma unroll
    for (int c = 0; c < 4; ++c) {
        const float* p = qp + c * 16 + hi * 8;
        float4 x = *(const float4*)p;
        float4 y = *(const float4*)(p + 4);
        int4v w = { (int)cvtpk(x.x * qs, x.y * qs), (int)cvtpk(x.z * qs, x.w * qs),
                    (int)cvtpk(y.x * qs, y.y * qs), (int)cvtpk(y.z * qs, y.w * qs) };
        qf[c] = __builtin_bit_cast(short8, w);
    }

    f32x16 acc0 = {0,0,0,0,0,0,0,0,0,0,0,0,0,0,0,0};
    f32x16 acc1 = {0,0,0,0,0,0,0,0,0,0,0,0,0,0,0,0};
    float l = 0.0f;

    // staging coords (within half): K by (key=t255>>2, dseg=(t255&3)*16 floats)
    const int skey = t255 >> 2, sds2 = (t255 & 3) * 32;
    const int swzk = (skey & 7) << 4;
    const int kwb = skey * 128;
    const int vkey2 = lane * 2;
    const int vds = qw * 16;

    // per-lane swizzled read bases (byte offsets within one 8KB buffer)
    const int krow0 = l31 * 128;
    const int krow1 = (32 + l31) * 128;
    const int kx = (hi * 16) ^ ((l31 & 7) << 4);
    const int vrow0 = l31 * 128;
    const int vrow1 = (32 + l31) * 128;

    const int soff = h * 1024;  // this half's first key
    const float* kpt = K + (size_t)bh * S * D + (size_t)(soff + skey) * D + (t255 & 3) * 16;
    const float* vpt = V + (size_t)bh * S * D + (size_t)(soff + lane) * D + vds;

    float4 ka0, ka1, ka2, ka3, vb0, vb1, vb2, vb3;

    auto load_tile = [&]() {
        ka0 = ((const float4*)kpt)[0]; ka1 = ((const float4*)kpt)[1];
        ka2 = ((const float4*)kpt)[2]; ka3 = ((const float4*)kpt)[3];
        vb0 = ((const float4*)vpt)[0]; vb1 = ((const float4*)vpt)[1];
        vb2 = ((const float4*)vpt)[2]; vb3 = ((const float4*)vpt)[3];
        kpt += KVB * D; vpt += KVB * D;
    };
    auto write_tile = [&](int c) {
        char* kdst = (char*)kreg + (h * 2 + c) * 8192;
        char* vdst = (char*)vreg + (h * 2 + c) * 8192;
        int4v w0 = { (int)cvtpk(ka0.x,ka0.y), (int)cvtpk(ka0.z,ka0.w),
                     (int)cvtpk(ka1.x,ka1.y), (int)cvtpk(ka1.z,ka1.w) };
        int4v w1 = { (int)cvtpk(ka2.x,ka2.y), (int)cvtpk(ka2.z,ka2.w),
                     (int)cvtpk(ka3.x,ka3.y), (int)cvtpk(ka3.z,ka3.w) };
        *(int4v*)(kdst + kwb + (sds2 ^ swzk)) = w0;
        *(int4v*)(kdst + kwb + ((sds2 + 16) ^ swzk)) = w1;
        unsigned cc[8] = { cvtpk(vb0.x,vb0.y), cvtpk(vb0.z,vb0.w),
                           cvtpk(vb1.x,vb1.y), cvtpk(vb1.z,vb1.w),
                           cvtpk(vb2.x,vb2.y), cvtpk(vb2.z,vb2.w),
                           cvtpk(vb3.x,vb3.y), cvtpk(vb3.z,vb3.w) };
        #pragma unroll
        for (int i = 0; i < 16; ++i) {
            int row = vds + i;                                  // vds%16==0
            int off = row * 128 + (vkey2 ^ ((i & 7) << 4));     // (row&7)==(i&7)
            unsigned val = (i & 1) ? (cc[i >> 1] >> 16) : (cc[i >> 1] & 0xffffu);
            *(unsigned short*)(vdst + off) = (unsigned short)val;
        }
    };

    // prologue: tile 0 of this half -> buf 0
    load_tile();
    write_tile(0);
    __syncthreads();

    #pragma unroll 2
    for (int it = 0; it < NT; ++it) {
        const int cur = it & 1;
        const bool more = (it + 1 < NT);
        if (more) load_tile();   // issue-early: latency hides under compute

        const char* kc = (const char*)kreg + (h * 2 + cur) * 8192;
        const char* vc = (const char*)vreg + (h * 2 + cur) * 8192;
        const int ktoff = soff + it * KVB;

        // QK^T (swapped): S^T = K * Q^T; rows=key, cols=q
        f32x16 s0 = {0,0,0,0,0,0,0,0,0,0,0,0,0,0,0,0};
        f32x16 s1 = {0,0,0,0,0,0,0,0,0,0,0,0,0,0,0,0};
        __builtin_amdgcn_s_setprio(1);
        #pragma unroll
        for (int c = 0; c < 4; ++c) {
            short8 kaf = *(const short8*)(kc + krow0 + (kx ^ (c << 5)));
            short8 kbf = *(const short8*)(kc + krow1 + (kx ^ (c << 5)));
            s0 = __builtin_amdgcn_mfma_f32_32x32x16_bf16(kaf, qf[c], s0, 0, 0, 0);
            s1 = __builtin_amdgcn_mfma_f32_32x32x16_bf16(kbf, qf[c], s1, 0, 0, 0);
        }
        __builtin_amdgcn_s_setprio(0);

        // bias + exp2 + row-sum (lane-local; key = ktoff + rg*8+hi*4+j [+32])
        float rsp0 = 0.0f, rsp1 = 0.0f, rsp2 = 0.0f, rsp3 = 0.0f;
        #pragma unroll
        for (int rg = 0; rg < 4; ++rg) {
            float4 bz0 = *(const float4*)&bias_lds[ktoff + rg * 8 + hi * 4];
            float4 bz1 = *(const float4*)&bias_lds[ktoff + 32 + rg * 8 + hi * 4];
            const float* z0 = (const float*)&bz0;
            const float* z1 = (const float*)&bz1;
            float rp = 0.0f;
            #pragma unroll
            for (int j = 0; j < 4; ++j) {
                int r = rg * 4 + j;
                float e0 = EXP2(s0[r] + z0[j]);
                float e1 = EXP2(s1[r] + z1[j]);
                s0[r] = e0; s1[r] = e1;
                rp += e0 + e1;
            }
            if (rg == 0) rsp0 = rp; else if (rg == 1) rsp1 = rp;
            else if (rg == 2) rsp2 = rp; else rsp3 = rp;
        }
        float rs = (rsp0 + rsp1) + (rsp2 + rsp3);
        rs += __shfl_xor(rs, 32);
        l += rs;

        // pack P into PV A-frags: windows of 16 keys; half-swap via shfl
        short8 pw[4];
        #pragma unroll
        for (int w = 0; w < 4; ++w) {
            int r0 = (w & 1) * 8;
            float q0 = (w >> 1) ? s1[r0+0] : s0[r0+0];
            float q1 = (w >> 1) ? s1[r0+1] : s0[r0+1];
            float q2 = (w >> 1) ? s1[r0+2] : s0[r0+2];
            float q3 = (w >> 1) ? s1[r0+3] : s0[r0+3];
            float q4 = (w >> 1) ? s1[r0+4] : s0[r0+4];
            float q5 = (w >> 1) ? s1[r0+5] : s0[r0+5];
            float q6 = (w >> 1) ? s1[r0+6] : s0[r0+6];
            float q7 = (w >> 1) ? s1[r0+7] : s0[r0+7];
            unsigned x0 = cvtpk(q0, q1);
            unsigned x1 = cvtpk(q2, q3);
            unsigned x2 = cvtpk(q4, q5);
            unsigned x3 = cvtpk(q6, q7);
            unsigned sx0 = (unsigned)__shfl_xor((int)x0, 32);
            unsigned sx1 = (unsigned)__shfl_xor((int)x1, 32);
            unsigned sx2 = (unsigned)__shfl_xor((int)x2, 32);
            unsigned sx3 = (unsigned)__shfl_xor((int)x3, 32);
            int4v wv = { (int)(hi ? sx2 : x0),
                         (int)(hi ? sx3 : x1),
                         (int)(hi ? x2 : sx0),
                         (int)(hi ? x3 : sx1) };
            pw[w] = __builtin_bit_cast(short8, wv);
        }

        // PV: acc[dt] += P(32q x 16k) * V(16k x 32d)
        __builtin_amdgcn_s_setprio(1);
        #pragma unroll
        for (int w = 0; w < 4; ++w) {
            short8 vf0 = *(const short8*)(vc + vrow0 + (kx ^ (w << 5)));
            short8 vf1 = *(const short8*)(vc + vrow1 + (kx ^ (w << 5)));
            acc0 = __builtin_amdgcn_mfma_f32_32x32x16_bf16(pw[w], vf0, acc0, 0, 0, 0);
            acc1 = __builtin_amdgcn_mfma_f32_32x32x16_bf16(pw[w], vf1, acc1, 0, 0, 0);
        }
        __builtin_amdgcn_s_setprio(0);

        if (more) write_tile(cur ^ 1);
        __syncthreads();
    }

    // ---- in-LDS combine: half-B publishes partials, half-A merges + stores ----
    if (hi == 0) l_buf[wid][l31] = l;
    if (h == 1) {
        #pragma unroll
        for (int rg = 0; rg < 4; ++rg) {
            #pragma unroll
            for (int j = 0; j < 4; ++j) {
                int r = rg * 4 + j;
                int qr = rg * 8 + hi * 4 + j;
                obuf[(qw * 32 + qr) * 64 + l31] = acc0[r];
                obuf[(qw * 32 + qr) * 64 + 32 + l31] = acc1[r];
            }
        }
    }
    __syncthreads();
    if (h == 0) {
        float* ob = O + ((size_t)bh * S + qrow0) * D;
        #pragma unroll
        for (int rg = 0; rg < 4; ++rg) {
            float4 la = *(const float4*)&l_buf[qw][rg * 8 + hi * 4];
            float4 lb = *(const float4*)&l_buf[qw + 4][rg * 8 + hi * 4];
            const float* pa = (const float*)&la;
            const float* pb = (const float*)&lb;
            #pragma unroll
            for (int j = 0; j < 4; ++j) {
                int r = rg * 4 + j;
                int qr = rg * 8 + hi * 4 + j;
                float inv = 1.0f / (pa[j] + pb[j]);
                float o0 = acc0[r] + obuf[(qw * 32 + qr) * 64 + l31];
                float o1 = acc1[r] + obuf[(qw * 32 + qr) * 64 + 32 + l31];
                ob[qr * 64 + l31] = o0 * inv;
                ob[qr * 64 + 32 + l31] = o1 * inv;
            }
        }
    }
}

extern "C" void kernel_launch(void* const* d_in, const int* in_sizes, int n_in,
                              void* d_out, int out_size, void* d_ws, size_t ws_size,
                              hipStream_t stream) {
    const float* Q = (const float*)d_in[0];
    const float* K = (const float*)d_in[1];
    const float* V = (const float*)d_in[2];
    const int*   M = (const int*)d_in[3];
    float* O = (float*)d_out;
    attn_fwd8<<<dim3(512), dim3(512), 0, stream>>>(Q, K, V, M, O);
}

// Round 10
// 166.237 us; speedup vs baseline: 1.2596x; 1.2454x over previous
//
#include <hip/hip_runtime.h>

typedef __attribute__((ext_vector_type(8))) short short8;
typedef __attribute__((ext_vector_type(16))) float f32x16;
typedef __attribute__((ext_vector_type(4))) int int4v;

#define LOG2E 1.4426950408889634f

#if __has_builtin(__builtin_amdgcn_exp2f)
#define EXP2(x) __builtin_amdgcn_exp2f(x)
#else
#define EXP2(x) exp2f(x)
#endif

__device__ __forceinline__ unsigned cvtpk(float lo, float hi) {
    unsigned r;
    asm("v_cvt_pk_bf16_f32 %0, %1, %2" : "=v"(r) : "v"(lo), "v"(hi));
    return r;
}

// B=2 H=16 S=2048 D=64. 512-thread block = 8 waves: waves 0-3 = key-half A
// (keys 0..1023), waves 4-7 = half B (1024..2047); each wave owns 32 q rows.
// Per half: double-buffered K [key][d] + V^T [d][key] bf16 LDS, XOR-swizzled.
// Swapped QK^T (S^T = K*Q^T), static-shift softmax p = exp2(s + bias),
// bias = -24 (keep) / -inf (pad) -> split partials are ADDITIVE (no max fixup).
// Combine IN LDS: half-B writes unnormalized acc (aliased over K/V region) + l;
// half-A adds, normalizes by (lA+lB), stores. No workspace traffic.
//
// NOTE: no second __launch_bounds__ arg / no waves_per_eu attribute — R8/R9
// showed hipcc responds to it by capping VGPR at 64 -> massive scratch spills
// (VGPR_Count=64, FETCH 95MB, WRITE 105MB). Natural allocation (~108, like v3)
// gives 4 waves/EU since VGPR<=128 and LDS caps at 2 blocks/CU.
__global__ __launch_bounds__(512) void attn_fwd8(
    const float* __restrict__ Q, const float* __restrict__ K,
    const float* __restrict__ V, const int* __restrict__ M,
    float* __restrict__ O)
{
    constexpr int S = 2048, D = 64, KVB = 64, NT = 16;  // 16 tiles per half
    // carve: kreg [h][dbuf][64*64]ushort = 32KB, vreg same = 32KB; obuf aliases
    __shared__ __align__(16) char smem[65536];
    __shared__ float bias_lds[S];
    __shared__ float l_buf[8][32];

    unsigned short* kreg = (unsigned short*)smem;
    unsigned short* vreg = (unsigned short*)(smem + 32768);
    float* obuf = (float*)smem;   // 128 q x 64 d fp32, valid after final barrier

    const int t = threadIdx.x;
    const int lane = t & 63, wid = t >> 6;
    const int l31 = lane & 31, hi = lane >> 5;
    const int h = wid >> 2, qw = wid & 3;   // key-half, q-wave within half
    const int t255 = t & 255;               // thread index within half

    // XCD-bijective swizzle: 512 blocks = 8 XCD chunks of 64
    const int lin = blockIdx.x;
    const int wgid = (lin & 7) * 64 + (lin >> 3);
    const int bh = wgid >> 4;     // 0..31
    const int qblk = wgid & 15;   // 0..15
    const int b = bh >> 4;        // H = 16

    const int* mrow = M + b * S;
    for (int i = t; i < S; i += 512)
        bias_lds[i] = mrow[i] ? -24.0f : -__builtin_inff();

    // Q B-fragments (col=q=l31, k=hi*8+j per 16-d chunk), scaled by 0.125*log2e
    const int qrow0 = qblk * 128 + qw * 32;
    const float* qp = Q + ((size_t)bh * S + qrow0 + l31) * D;
    const float qs = 0.125f * LOG2E;
    short8 qf[4];
    #pragma unroll
    for (int c = 0; c < 4; ++c) {
        const float* p = qp + c * 16 + hi * 8;
        float4 x = *(const float4*)p;
        float4 y = *(const float4*)(p + 4);
        int4v w = { (int)cvtpk(x.x * qs, x.y * qs), (int)cvtpk(x.z * qs, x.w * qs),
                    (int)cvtpk(y.x * qs, y.y * qs), (int)cvtpk(y.z * qs, y.w * qs) };
        qf[c] = __builtin_bit_cast(short8, w);
    }

    f32x16 acc0 = {0,0,0,0,0,0,0,0,0,0,0,0,0,0,0,0};
    f32x16 acc1 = {0,0,0,0,0,0,0,0,0,0,0,0,0,0,0,0};
    float l = 0.0f;

    // staging coords (within half): K by (key=t255>>2, dseg=(t255&3)*16 floats)
    const int skey = t255 >> 2, sds2 = (t255 & 3) * 32;
    const int swzk = (skey & 7) << 4;
    const int kwb = skey * 128;
    const int vkey2 = lane * 2;
    const int vds = qw * 16;

    // per-lane swizzled read bases (byte offsets within one 8KB buffer)
    const int krow0 = l31 * 128;
    const int krow1 = (32 + l31) * 128;
    const int kx = (hi * 16) ^ ((l31 & 7) << 4);
    const int vrow0 = l31 * 128;
    const int vrow1 = (32 + l31) * 128;

    const int soff = h * 1024;  // this half's first key
    const float* kpt = K + (size_t)bh * S * D + (size_t)(soff + skey) * D + (t255 & 3) * 16;
    const float* vpt = V + (size_t)bh * S * D + (size_t)(soff + lane) * D + vds;

    float4 ka0, ka1, ka2, ka3, vb0, vb1, vb2, vb3;

    auto load_tile = [&]() {
        ka0 = ((const float4*)kpt)[0]; ka1 = ((const float4*)kpt)[1];
        ka2 = ((const float4*)kpt)[2]; ka3 = ((const float4*)kpt)[3];
        vb0 = ((const float4*)vpt)[0]; vb1 = ((const float4*)vpt)[1];
        vb2 = ((const float4*)vpt)[2]; vb3 = ((const float4*)vpt)[3];
        kpt += KVB * D; vpt += KVB * D;
    };
    auto write_tile = [&](int c) {
        char* kdst = (char*)kreg + (h * 2 + c) * 8192;
        char* vdst = (char*)vreg + (h * 2 + c) * 8192;
        int4v w0 = { (int)cvtpk(ka0.x,ka0.y), (int)cvtpk(ka0.z,ka0.w),
                     (int)cvtpk(ka1.x,ka1.y), (int)cvtpk(ka1.z,ka1.w) };
        int4v w1 = { (int)cvtpk(ka2.x,ka2.y), (int)cvtpk(ka2.z,ka2.w),
                     (int)cvtpk(ka3.x,ka3.y), (int)cvtpk(ka3.z,ka3.w) };
        *(int4v*)(kdst + kwb + (sds2 ^ swzk)) = w0;
        *(int4v*)(kdst + kwb + ((sds2 + 16) ^ swzk)) = w1;
        unsigned cc[8] = { cvtpk(vb0.x,vb0.y), cvtpk(vb0.z,vb0.w),
                           cvtpk(vb1.x,vb1.y), cvtpk(vb1.z,vb1.w),
                           cvtpk(vb2.x,vb2.y), cvtpk(vb2.z,vb2.w),
                           cvtpk(vb3.x,vb3.y), cvtpk(vb3.z,vb3.w) };
        #pragma unroll
        for (int i = 0; i < 16; ++i) {
            int row = vds + i;                                  // vds%16==0
            int off = row * 128 + (vkey2 ^ ((i & 7) << 4));     // (row&7)==(i&7)
            unsigned val = (i & 1) ? (cc[i >> 1] >> 16) : (cc[i >> 1] & 0xffffu);
            *(unsigned short*)(vdst + off) = (unsigned short)val;
        }
    };

    // prologue: tile 0 of this half -> buf 0
    load_tile();
    write_tile(0);
    __syncthreads();

    #pragma unroll 2
    for (int it = 0; it < NT; ++it) {
        const int cur = it & 1;
        const bool more = (it + 1 < NT);
        if (more) load_tile();   // issue-early: latency hides under compute

        const char* kc = (const char*)kreg + (h * 2 + cur) * 8192;
        const char* vc = (const char*)vreg + (h * 2 + cur) * 8192;
        const int ktoff = soff + it * KVB;

        // QK^T (swapped): S^T = K * Q^T; rows=key, cols=q
        f32x16 s0 = {0,0,0,0,0,0,0,0,0,0,0,0,0,0,0,0};
        f32x16 s1 = {0,0,0,0,0,0,0,0,0,0,0,0,0,0,0,0};
        __builtin_amdgcn_s_setprio(1);
        #pragma unroll
        for (int c = 0; c < 4; ++c) {
            short8 kaf = *(const short8*)(kc + krow0 + (kx ^ (c << 5)));
            short8 kbf = *(const short8*)(kc + krow1 + (kx ^ (c << 5)));
            s0 = __builtin_amdgcn_mfma_f32_32x32x16_bf16(kaf, qf[c], s0, 0, 0, 0);
            s1 = __builtin_amdgcn_mfma_f32_32x32x16_bf16(kbf, qf[c], s1, 0, 0, 0);
        }
        __builtin_amdgcn_s_setprio(0);

        // bias + exp2 + row-sum (lane-local; key = ktoff + rg*8+hi*4+j [+32])
        float rsp0 = 0.0f, rsp1 = 0.0f, rsp2 = 0.0f, rsp3 = 0.0f;
        #pragma unroll
        for (int rg = 0; rg < 4; ++rg) {
            float4 bz0 = *(const float4*)&bias_lds[ktoff + rg * 8 + hi * 4];
            float4 bz1 = *(const float4*)&bias_lds[ktoff + 32 + rg * 8 + hi * 4];
            const float* z0 = (const float*)&bz0;
            const float* z1 = (const float*)&bz1;
            float rp = 0.0f;
            #pragma unroll
            for (int j = 0; j < 4; ++j) {
                int r = rg * 4 + j;
                float e0 = EXP2(s0[r] + z0[j]);
                float e1 = EXP2(s1[r] + z1[j]);
                s0[r] = e0; s1[r] = e1;
                rp += e0 + e1;
            }
            if (rg == 0) rsp0 = rp; else if (rg == 1) rsp1 = rp;
            else if (rg == 2) rsp2 = rp; else rsp3 = rp;
        }
        float rs = (rsp0 + rsp1) + (rsp2 + rsp3);
        rs += __shfl_xor(rs, 32);
        l += rs;

        // pack P into PV A-frags: windows of 16 keys; half-swap via shfl
        short8 pw[4];
        #pragma unroll
        for (int w = 0; w < 4; ++w) {
            int r0 = (w & 1) * 8;
            float q0 = (w >> 1) ? s1[r0+0] : s0[r0+0];
            float q1 = (w >> 1) ? s1[r0+1] : s0[r0+1];
            float q2 = (w >> 1) ? s1[r0+2] : s0[r0+2];
            float q3 = (w >> 1) ? s1[r0+3] : s0[r0+3];
            float q4 = (w >> 1) ? s1[r0+4] : s0[r0+4];
            float q5 = (w >> 1) ? s1[r0+5] : s0[r0+5];
            float q6 = (w >> 1) ? s1[r0+6] : s0[r0+6];
            float q7 = (w >> 1) ? s1[r0+7] : s0[r0+7];
            unsigned x0 = cvtpk(q0, q1);
            unsigned x1 = cvtpk(q2, q3);
            unsigned x2 = cvtpk(q4, q5);
            unsigned x3 = cvtpk(q6, q7);
            unsigned sx0 = (unsigned)__shfl_xor((int)x0, 32);
            unsigned sx1 = (unsigned)__shfl_xor((int)x1, 32);
            unsigned sx2 = (unsigned)__shfl_xor((int)x2, 32);
            unsigned sx3 = (unsigned)__shfl_xor((int)x3, 32);
            int4v wv = { (int)(hi ? sx2 : x0),
                         (int)(hi ? sx3 : x1),
                         (int)(hi ? x2 : sx0),
                         (int)(hi ? x3 : sx1) };
            pw[w] = __builtin_bit_cast(short8, wv);
        }

        // PV: acc[dt] += P(32q x 16k) * V(16k x 32d)
        __builtin_amdgcn_s_setprio(1);
        #pragma unroll
        for (int w = 0; w < 4; ++w) {
            short8 vf0 = *(const short8*)(vc + vrow0 + (kx ^ (w << 5)));
            short8 vf1 = *(const short8*)(vc + vrow1 + (kx ^ (w << 5)));
            acc0 = __builtin_amdgcn_mfma_f32_32x32x16_bf16(pw[w], vf0, acc0, 0, 0, 0);
            acc1 = __builtin_amdgcn_mfma_f32_32x32x16_bf16(pw[w], vf1, acc1, 0, 0, 0);
        }
        __builtin_amdgcn_s_setprio(0);

        if (more) write_tile(cur ^ 1);
        __syncthreads();
    }

    // ---- in-LDS combine: half-B publishes partials, half-A merges + stores ----
    if (hi == 0) l_buf[wid][l31] = l;
    if (h == 1) {
        #pragma unroll
        for (int rg = 0; rg < 4; ++rg) {
            #pragma unroll
            for (int j = 0; j < 4; ++j) {
                int r = rg * 4 + j;
                int qr = rg * 8 + hi * 4 + j;
                obuf[(qw * 32 + qr) * 64 + l31] = acc0[r];
                obuf[(qw * 32 + qr) * 64 + 32 + l31] = acc1[r];
            }
        }
    }
    __syncthreads();
    if (h == 0) {
        float* ob = O + ((size_t)bh * S + qrow0) * D;
        #pragma unroll
        for (int rg = 0; rg < 4; ++rg) {
            float4 la = *(const float4*)&l_buf[qw][rg * 8 + hi * 4];
            float4 lb = *(const float4*)&l_buf[qw + 4][rg * 8 + hi * 4];
            const float* pa = (const float*)&la;
            const float* pb = (const float*)&lb;
            #pragma unroll
            for (int j = 0; j < 4; ++j) {
                int r = rg * 4 + j;
                int qr = rg * 8 + hi * 4 + j;
                float inv = 1.0f / (pa[j] + pb[j]);
                float o0 = acc0[r] + obuf[(qw * 32 + qr) * 64 + l31];
                float o1 = acc1[r] + obuf[(qw * 32 + qr) * 64 + 32 + l31];
                ob[qr * 64 + l31] = o0 * inv;
                ob[qr * 64 + 32 + l31] = o1 * inv;
            }
        }
    }
}

extern "C" void kernel_launch(void* const* d_in, const int* in_sizes, int n_in,
                              void* d_out, int out_size, void* d_ws, size_t ws_size,
                              hipStream_t stream) {
    const float* Q = (const float*)d_in[0];
    const float* K = (const float*)d_in[1];
    const float* V = (const float*)d_in[2];
    const int*   M = (const int*)d_in[3];
    float* O = (float*)d_out;
    attn_fwd8<<<dim3(512), dim3(512), 0, stream>>>(Q, K, V, M, O);
}